// Round 13
// baseline (281.694 us; speedup 1.0000x reference)
//
#include <hip/hip_runtime.h>
#include <math.h>

// Problem constants
#define B_   16
#define QL_  512
#define VL_  512
#define HID_ 1024
#define NH_  4
#define CH_  10
#define DIM_ 256

typedef __attribute__((ext_vector_type(4))) float f32x4;
typedef __attribute__((ext_vector_type(8))) short bf16x8;
typedef long long ll;

__device__ __forceinline__ ushort f2bf(float f) {
    union { float f; uint32_t u; } c; c.f = f;
    uint32_t u = c.u;
    u += 0x7fffu + ((u >> 16) & 1u);
    return (ushort)(u >> 16);
}

__device__ __forceinline__ void gload16(const void* g, void* l) {
    __builtin_amdgcn_global_load_lds((const __attribute__((address_space(1))) void*)g,
                                     (__attribute__((address_space(3))) void*)l,
                                     16, 0, 0);
}

// ====== gemm32: 128x128, BK=32 dbuf (32 KB LDS), counted vmcnt, CORRECT swizzle ======
// C = op((A @ Bt^T) + bias) * scale. A: M x K bf16 (lda). Bt: N x K bf16 (ldb).
// flags: 1 = bf16 C, 2 = tanh, 8 = kkvv split (cols>=1024 -> Cv2 transposed, ld 8192).
// Swizzle: 64B rows (4x16B granules); bank-quad = (row&1)*4 + slot&3. Correct perm:
// slot ^= (row>>1)&3  (uses parity-free bits; verified 0-conflict in scores kernel).
// Sync: stage(t+1) -> vmcnt(4) [own 4 landed, next 4 in flight] -> barrier -> MFMA -> barrier.
__global__ __launch_bounds__(256)
void gemm32(const ushort* __restrict__ A, const ushort* __restrict__ Bt,
            void* __restrict__ Cv, void* __restrict__ Cv2,
            const float* __restrict__ bias,
            int K, int lda, int ldb, int ldc,
            float post_scale, int flags)
{
    __shared__ ushort As[2][128 * 32];
    __shared__ ushort Bs[2][128 * 32];

    // T1 bijective chunked swizzle (nwg % 8 == 0 for all uses)
    int gx = gridDim.x, nwg = gx * gridDim.y;
    int flat = blockIdx.y * gx + blockIdx.x;
    int q = nwg >> 3, r = nwg & 7;
    int xcd = flat & 7, idx = flat >> 3;
    int logical = (xcd < r ? xcd * (q + 1) : r * (q + 1) + (xcd - r) * q) + idx;
    int brow = (logical / gx) * 128;
    int bcol = (logical % gx) * 128;

    int t = threadIdx.x;
    int lane = t & 63, w = t >> 6;
    int wr = (w >> 1) * 64, wc = (w & 1) * 64;

    // staging: 512 granules per matrix; thread t -> rows (t>>2) and 64+(t>>2), slot t&3.
    // f(row) = (row>>1)&3; f(r) == f(r+64) since 64 is multiple of 8.
    int srow = t >> 2, sslot = t & 3;
    int sk = ((sslot ^ ((srow >> 1) & 3)) << 3);
    const ushort* gaBase = A  + (ll)(brow + srow) * lda + sk;
    const ushort* gbBase = Bt + (ll)(bcol + srow) * ldb + sk;

    f32x4 acc[4][4] = {};

    auto stage = [&](int buf, int k0) {
        ushort* la = &As[buf][t * 8];
        ushort* lb = &Bs[buf][t * 8];
        gload16(gaBase + k0, la);
        gload16(gaBase + (ll)64 * lda + k0, la + 2048);
        gload16(gbBase + k0, lb);
        gload16(gbBase + (ll)64 * ldb + k0, lb + 2048);
    };

    int NT = K >> 5;
    stage(0, 0);
    int cur = 0;
    int slotR = (lane >> 4) ^ ((lane >> 1) & 3);   // row = wr|wc + (lane&15); f(row) = (lane>>1)&3
    for (int tI = 0; tI < NT; ++tI) {
        if (tI + 1 < NT) {
            stage(cur ^ 1, (tI + 1) << 5);                    // next tile's 4 loads in flight
            asm volatile("s_waitcnt vmcnt(4)" ::: "memory");  // own 4 landed
        } else {
            asm volatile("s_waitcnt vmcnt(0)" ::: "memory");
        }
        __builtin_amdgcn_s_barrier();
        __builtin_amdgcn_sched_barrier(0);

        const ushort* ab = &As[cur][(wr + (lane & 15)) * 32 + slotR * 8];
        const ushort* bb = &Bs[cur][(wc + (lane & 15)) * 32 + slotR * 8];
        bf16x8 af[4], bfr[4];
        #pragma unroll
        for (int m = 0; m < 4; ++m) af[m]  = *(const bf16x8*)(ab + m * 512);
        #pragma unroll
        for (int n = 0; n < 4; ++n) bfr[n] = *(const bf16x8*)(bb + n * 512);
        #pragma unroll
        for (int m = 0; m < 4; ++m)
            #pragma unroll
            for (int n = 0; n < 4; ++n)
                acc[m][n] = __builtin_amdgcn_mfma_f32_16x16x32_bf16(af[m], bfr[n], acc[m][n], 0, 0, 0);

        __builtin_amdgcn_s_barrier();
        __builtin_amdgcn_sched_barrier(0);
        cur ^= 1;
    }

    float*  Cf = (float*)Cv;
    ushort* Cb = (ushort*)Cv;
    ushort* C2 = (ushort*)Cv2;
    #pragma unroll
    for (int m = 0; m < 4; ++m) {
        int r0 = brow + wr + m * 16 + (lane >> 4) * 4;
        #pragma unroll
        for (int n = 0; n < 4; ++n) {
            int c = bcol + wc + n * 16 + (lane & 15);
            float bv = bias ? bias[c] : 0.0f;
            float v0 = (acc[m][n][0] + bv) * post_scale;
            float v1 = (acc[m][n][1] + bv) * post_scale;
            float v2 = (acc[m][n][2] + bv) * post_scale;
            float v3 = (acc[m][n][3] + bv) * post_scale;
            if (flags & 2) { v0 = tanhf(v0); v1 = tanhf(v1); v2 = tanhf(v2); v3 = tanhf(v3); }
            if ((flags & 8) && c >= 1024) {
                ushort4 o;
                o.x = f2bf(v0); o.y = f2bf(v1); o.z = f2bf(v2); o.w = f2bf(v3);
                *(ushort4*)&C2[(ll)(c - 1024) * 8192 + r0] = o;
            } else if (flags & 1) {
                Cb[(ll)(r0 + 0) * ldc + c] = f2bf(v0);
                Cb[(ll)(r0 + 1) * ldc + c] = f2bf(v1);
                Cb[(ll)(r0 + 2) * ldc + c] = f2bf(v2);
                Cb[(ll)(r0 + 3) * ldc + c] = f2bf(v3);
            } else {
                Cf[(ll)(r0 + 0) * ldc + c] = v0;
                Cf[(ll)(r0 + 1) * ldc + c] = v1;
                Cf[(ll)(r0 + 2) * ldc + c] = v2;
                Cf[(ll)(r0 + 3) * ldc + c] = v3;
            }
        }
    }
}

// ============ gemm_bf16: 128x128, BK=64 dbuf, counted-vmcnt (R9-proven) — ctx & folds ======
__global__ __launch_bounds__(256)
void gemm_bf16(const ushort* __restrict__ A, const ushort* __restrict__ Bt,
               void* __restrict__ Cv, void* __restrict__ Cv2,
               const float* __restrict__ bias,
               int K, int lda, int ldb, int ldc,
               long long a1, long long a2, long long b1, long long b2,
               long long c1, long long c2, int WB,
               float post_scale, int flags)
{
    __shared__ ushort As[2][128 * 64];
    __shared__ ushort Bs[2][128 * 64];

    int z = blockIdx.z;
    int zm = z % WB, zd = z / WB;
    A  += a1 * zm + a2 * zd;
    Bt += b1 * zm + b2 * zd;
    long long coff = c1 * (long long)zm + c2 * (long long)zd;

    int gx = gridDim.x;
    int nwg = gx * gridDim.y;
    int flat = blockIdx.y * gx + blockIdx.x;
    int q = nwg >> 3, r = nwg & 7;
    int xcd = flat & 7, idx = flat >> 3;
    int logical = (xcd < r ? xcd * (q + 1) : r * (q + 1) + (xcd - r) * q) + idx;
    int brow = (logical / gx) * 128;
    int bcol = (logical % gx) * 128;

    int t = threadIdx.x;
    int lane = t & 63, w = t >> 6;
    int wr = (w >> 1) * 64, wc = (w & 1) * 64;

    int srow  = t >> 3;
    int sslot = t & 7;
    int sk = ((sslot ^ (srow & 7)) << 3);
    const ushort* gaBase = A  + (long long)(brow + srow) * lda + sk;
    const ushort* gbBase = Bt + (long long)(bcol + srow) * ldb + sk;

    f32x4 acc[4][4] = {};

    auto stage = [&](int buf, int k0) {
        ushort* la = &As[buf][t * 8];
        ushort* lb = &Bs[buf][t * 8];
        #pragma unroll
        for (int i = 0; i < 4; ++i) {
            gload16(gaBase + (long long)(i * 32) * lda + k0, la + i * 2048);
            gload16(gbBase + (long long)(i * 32) * ldb + k0, lb + i * 2048);
        }
    };

    int NT = K >> 6;
    stage(0, 0);
    int cur = 0;
    for (int tI = 0; tI < NT; ++tI) {
        if (tI + 1 < NT) {
            stage(cur ^ 1, (tI + 1) << 6);
            asm volatile("s_waitcnt vmcnt(8)" ::: "memory");
        } else {
            asm volatile("s_waitcnt vmcnt(0)" ::: "memory");
        }
        __builtin_amdgcn_s_barrier();
        __builtin_amdgcn_sched_barrier(0);

        #pragma unroll
        for (int kk = 0; kk < 2; ++kk) {
            int slot = ((kk << 2) + (lane >> 4)) ^ (lane & 7);
            const ushort* ab = &As[cur][(wr + (lane & 15)) * 64 + slot * 8];
            const ushort* bb = &Bs[cur][(wc + (lane & 15)) * 64 + slot * 8];
            bf16x8 af[4], bfr[4];
            #pragma unroll
            for (int m = 0; m < 4; ++m) af[m]  = *(const bf16x8*)(ab + m * 1024);
            #pragma unroll
            for (int n = 0; n < 4; ++n) bfr[n] = *(const bf16x8*)(bb + n * 1024);
            #pragma unroll
            for (int m = 0; m < 4; ++m)
                #pragma unroll
                for (int n = 0; n < 4; ++n)
                    acc[m][n] = __builtin_amdgcn_mfma_f32_16x16x32_bf16(af[m], bfr[n], acc[m][n], 0, 0, 0);
        }

        __builtin_amdgcn_s_barrier();
        __builtin_amdgcn_sched_barrier(0);
        cur ^= 1;
    }

    float*  Cf = (float*)Cv + coff;
    ushort* Cb = (ushort*)Cv + coff;
    ushort* C2 = (ushort*)Cv2;
    #pragma unroll
    for (int m = 0; m < 4; ++m) {
        int r0 = brow + wr + m * 16 + (lane >> 4) * 4;
        #pragma unroll
        for (int n = 0; n < 4; ++n) {
            int c = bcol + wc + n * 16 + (lane & 15);
            float bv = bias ? bias[c] : 0.0f;
            float v0 = (acc[m][n][0] + bv) * post_scale;
            float v1 = (acc[m][n][1] + bv) * post_scale;
            float v2 = (acc[m][n][2] + bv) * post_scale;
            float v3 = (acc[m][n][3] + bv) * post_scale;
            if (flags & 2) { v0 = tanhf(v0); v1 = tanhf(v1); v2 = tanhf(v2); v3 = tanhf(v3); }
            if ((flags & 8) && c >= 1024) {
                ushort4 o;
                o.x = f2bf(v0); o.y = f2bf(v1); o.z = f2bf(v2); o.w = f2bf(v3);
                *(ushort4*)&C2[(long long)(c - 1024) * 8192 + r0] = o;
            } else if (flags & 1) {
                Cb[(long long)(r0 + 0) * ldc + c] = f2bf(v0);
                Cb[(long long)(r0 + 1) * ldc + c] = f2bf(v1);
                Cb[(long long)(r0 + 2) * ldc + c] = f2bf(v2);
                Cb[(long long)(r0 + 3) * ldc + c] = f2bf(v3);
            } else {
                Cf[(long long)(r0 + 0) * ldc + c] = v0;
                Cf[(long long)(r0 + 1) * ldc + c] = v1;
                Cf[(long long)(r0 + 2) * ldc + c] = v2;
                Cf[(long long)(r0 + 3) * ldc + c] = v3;
            }
        }
    }
}

// ======= fused scores + softmax, BK=32 dbuf + counted vmcnt (R12-proven) ==========
__global__ __launch_bounds__(512, 1)
void scores_softmax(const ushort* __restrict__ qq, const ushort* __restrict__ kk,
                    float* __restrict__ attn, ushort* __restrict__ attnb)
{
    __shared__ ushort As[2][128 * 32];
    __shared__ ushort Bs[2][512 * 32];
    __shared__ float redm[4][128];
    __shared__ float reds[4][128];

    int z = blockIdx.z;              // n = h*16 + b
    int b = z & 15, h = z >> 4;
    const ushort* Abase = qq + (ll)b * 524288 + h * 256;
    const ushort* Bbase = kk + (ll)b * 524288 + h * 256;
    float*  aout = attn  + (ll)z * 262144;
    ushort* bout = attnb + (ll)z * 262144;

    int brow = blockIdx.y * 128;

    int t = threadIdx.x;
    int lane = t & 63, w = t >> 6;
    int wr = (w >> 2) * 64;
    int wc = (w & 3) * 128;

    int srow = t >> 2, sslot = t & 3;
    int sk = ((sslot ^ ((srow >> 1) & 3)) << 3);
    const ushort* ga = Abase + (ll)(brow + srow) * 1024 + sk;
    const ushort* gb = Bbase + (ll)srow * 1024 + sk;

    f32x4 acc[4][8] = {};

    auto stage = [&](int buf, int k0) {
        gload16(ga + k0, &As[buf][t * 8]);
        #pragma unroll
        for (int i = 0; i < 4; ++i)
            gload16(gb + (ll)(i * 128) * 1024 + k0, &Bs[buf][t * 8 + i * 4096]);
    };

    int cur = 0;
    stage(0, 0);
    #pragma unroll
    for (int tI = 0; tI < 8; ++tI) {
        if (tI + 1 < 8) {
            stage(cur ^ 1, (tI + 1) << 5);
            asm volatile("s_waitcnt vmcnt(5)" ::: "memory");
        } else {
            asm volatile("s_waitcnt vmcnt(0)" ::: "memory");
        }
        __builtin_amdgcn_s_barrier();
        __builtin_amdgcn_sched_barrier(0);

        int slot = (lane >> 4) ^ ((lane >> 1) & 3);
        const ushort* ab = &As[cur][(wr + (lane & 15)) * 32 + slot * 8];
        const ushort* bb = &Bs[cur][(wc + (lane & 15)) * 32 + slot * 8];
        bf16x8 af[4], bfr[8];
        #pragma unroll
        for (int m = 0; m < 4; ++m) af[m]  = *(const bf16x8*)(ab + m * 512);
        #pragma unroll
        for (int n = 0; n < 8; ++n) bfr[n] = *(const bf16x8*)(bb + n * 512);
        #pragma unroll
        for (int m = 0; m < 4; ++m)
            #pragma unroll
            for (int n = 0; n < 8; ++n)
                acc[m][n] = __builtin_amdgcn_mfma_f32_16x16x32_bf16(af[m], bfr[n], acc[m][n], 0, 0, 0);

        __builtin_amdgcn_s_barrier();
        __builtin_amdgcn_sched_barrier(0);
        cur ^= 1;
    }

    float rmax[4][4], rinv[4][4];
    #pragma unroll
    for (int m = 0; m < 4; ++m)
        #pragma unroll
        for (int j = 0; j < 4; ++j) {
            float pm = acc[m][0][j];
            #pragma unroll
            for (int n = 1; n < 8; ++n) pm = fmaxf(pm, acc[m][n][j]);
            pm = fmaxf(pm, __shfl_xor(pm, 1));
            pm = fmaxf(pm, __shfl_xor(pm, 2));
            pm = fmaxf(pm, __shfl_xor(pm, 4));
            pm = fmaxf(pm, __shfl_xor(pm, 8));
            if ((lane & 15) == 0)
                redm[w & 3][wr + m * 16 + (lane >> 4) * 4 + j] = pm;
        }
    __syncthreads();
    #pragma unroll
    for (int m = 0; m < 4; ++m)
        #pragma unroll
        for (int j = 0; j < 4; ++j) {
            int row = wr + m * 16 + (lane >> 4) * 4 + j;
            rmax[m][j] = fmaxf(fmaxf(redm[0][row], redm[1][row]),
                               fmaxf(redm[2][row], redm[3][row]));
        }
    #pragma unroll
    for (int m = 0; m < 4; ++m)
        #pragma unroll
        for (int j = 0; j < 4; ++j) {
            float ps = 0.f;
            #pragma unroll
            for (int n = 0; n < 8; ++n) {
                float e = __expf(acc[m][n][j] - rmax[m][j]);
                acc[m][n][j] = e;
                ps += e;
            }
            ps += __shfl_xor(ps, 1);
            ps += __shfl_xor(ps, 2);
            ps += __shfl_xor(ps, 4);
            ps += __shfl_xor(ps, 8);
            if ((lane & 15) == 0)
                reds[w & 3][wr + m * 16 + (lane >> 4) * 4 + j] = ps;
        }
    __syncthreads();
    #pragma unroll
    for (int m = 0; m < 4; ++m)
        #pragma unroll
        for (int j = 0; j < 4; ++j) {
            int row = wr + m * 16 + (lane >> 4) * 4 + j;
            rinv[m][j] = 1.0f / (reds[0][row] + reds[1][row] + reds[2][row] + reds[3][row]);
        }
    #pragma unroll
    for (int m = 0; m < 4; ++m) {
        int r0 = brow + wr + m * 16 + (lane >> 4) * 4;
        #pragma unroll
        for (int n = 0; n < 8; ++n) {
            int c = wc + n * 16 + (lane & 15);
            #pragma unroll
            for (int j = 0; j < 4; ++j) {
                float v = acc[m][n][j] * rinv[m][j];
                aout[(ll)(r0 + j) * 512 + c] = v;
                bout[(ll)(r0 + j) * 512 + c] = f2bf(v);
            }
        }
    }
}

// ================= merged prep kernels =================
__global__ __launch_bounds__(256)
void prep_acts(const float* __restrict__ query, const float* __restrict__ value,
               const float* __restrict__ prev, const float* __restrict__ cw,
               const float* __restrict__ cb,
               ushort* __restrict__ Acat, ushort* __restrict__ vext)
{
    int bI = blockIdx.x;
    if (bI < 16384) {
        const float* in = (bI < 8192) ? query : value;
        ushort* out = (bI < 8192) ? Acat : vext;
        int ld_out = (bI < 8192) ? 2048 : 1088;
        ll idx = (ll)(bI & 8191) * 256 + threadIdx.x;
        ll row = idx >> 8;
        int c4 = (int)(idx & 255) * 4;
        float4 v = *(const float4*)&in[row * 1024 + c4];
        ushort4 o;
        o.x = f2bf(v.x); o.y = f2bf(v.y); o.z = f2bf(v.z); o.w = f2bf(v.w);
        *(ushort4*)&out[row * ld_out + c4] = o;
    } else {
        int idx = (bI - 16384) * 256 + threadIdx.x;
        int row = idx >> 6, j = idx & 63;
        int b = row >> 9, l = row & 511;
        ushort v = 0;
        if (j < 40) {
            int h = j / 10, c = j - h * 10;
            const float* p = prev + (ll)(b * 4 + h) * VL_;
            float xm = (l > 0)       ? p[l - 1] : 0.f;
            float x0 = p[l];
            float xp = (l < VL_ - 1) ? p[l + 1] : 0.f;
            v = f2bf(xm * cw[c * 3 + 0] + x0 * cw[c * 3 + 1] + xp * cw[c * 3 + 2] + cb[c]);
        }
        vext[(ll)row * 1088 + 1024 + j] = v;
    }
}

__global__ __launch_bounds__(256)
void prep_w(const float* __restrict__ Wq, const float* __restrict__ Wv,
            ushort* __restrict__ Wqb, ushort* __restrict__ Wvb,
            const float* __restrict__ bq, const float* __restrict__ sbq, const float* __restrict__ swq,
            const float* __restrict__ bias, const float* __restrict__ sbk, const float* __restrict__ swk,
            const float* __restrict__ sbv, const float* __restrict__ swv,
            const float* __restrict__ Wloc,
            float* __restrict__ bqq, float* __restrict__ bkv,
            float* __restrict__ wlK, float* __restrict__ wlV)
{
    int bI = blockIdx.x;
    if (bI < 2048) {
        const float* in = (bI < 1024) ? Wq : Wv;
        ushort* out = (bI < 1024) ? Wqb : Wvb;
        ll idx = (ll)(bI & 1023) * 256 + threadIdx.x;
        ll row = idx >> 8;
        int c4 = (int)(idx & 255) * 4;
        float4 v = *(const float4*)&in[row * 1024 + c4];
        ushort4 o;
        o.x = f2bf(v.x); o.y = f2bf(v.y); o.z = f2bf(v.z); o.w = f2bf(v.w);
        *(ushort4*)&out[row * 1024 + c4] = o;
        return;
    }
    int idx = (bI - 2048) * 256 + threadIdx.x;
    if (idx < 1024) {
        int h = idx >> 8, d = idx & 255;
        float s = 0.f;
        for (int j = 0; j < 256; ++j) s += bq[h * 256 + j] * swq[j * 256 + d];
        bqq[idx] = s + sbq[d];
    } else if (idx < 3072) {
        int i = idx - 1024;
        int kv = i >> 10, ii = i & 1023;
        int h = ii >> 8, d = ii & 255;
        const float* sw = kv ? swv : swk;
        const float* sb = kv ? sbv : sbk;
        float s = 0.f;
        for (int j = 0; j < 256; ++j) s += bias[h * 256 + j] * sw[j * 256 + d];
        bkv[i] = s + sb[d];
    } else if (idx < 5632) {
        int i = idx - 3072; int c = i >> 8, d = i & 255;
        float s = 0.f;
        for (int j = 0; j < 256; ++j) s += Wloc[c * 256 + j] * swk[j * 256 + d];
        wlK[i] = s;
    } else if (idx < 8192) {
        int i = idx - 5632; int c = i >> 8, d = i & 255;
        float s = 0.f;
        for (int j = 0; j < 256; ++j) s += Wloc[c * 256 + j] * swv[j * 256 + d];
        wlV[i] = s;
    }
}

__global__ __launch_bounds__(256)
void transpose_cast(const float* __restrict__ in, ushort* __restrict__ out, int R, int C, int ld_out)
{
    __shared__ float tile[64][65];
    int r0 = blockIdx.y * 64, c0 = blockIdx.x * 64;
    int t = threadIdx.x;
    int tr = t >> 2, tc = (t & 3) * 16;
    const float* ip = in + (ll)(r0 + tr) * C + c0 + tc;
    #pragma unroll
    for (int i = 0; i < 4; ++i) {
        float4 v = *(const float4*)(ip + i * 4);
        tile[tr][tc + i * 4 + 0] = v.x;
        tile[tr][tc + i * 4 + 1] = v.y;
        tile[tr][tc + i * 4 + 2] = v.z;
        tile[tr][tc + i * 4 + 3] = v.w;
    }
    __syncthreads();
    int cl = t >> 2, rl = (t & 3) * 16;
    ushort* op = out + (ll)(c0 + cl) * ld_out + r0 + rl;
    #pragma unroll
    for (int i = 0; i < 16; ++i) op[i] = f2bf(tile[rl + i][cl]);
}

__global__ __launch_bounds__(256)
void sw3_transpose(const float* __restrict__ swq, const float* __restrict__ swk,
                   const float* __restrict__ swv, ushort* __restrict__ oq,
                   ushort* __restrict__ ok, ushort* __restrict__ ov)
{
    __shared__ float tile[64][65];
    const float* in = (blockIdx.z == 0) ? swq : (blockIdx.z == 1) ? swk : swv;
    ushort* out     = (blockIdx.z == 0) ? oq  : (blockIdx.z == 1) ? ok  : ov;
    int r0 = blockIdx.y * 64, c0 = blockIdx.x * 64;
    int t = threadIdx.x;
    int tr = t >> 2, tc = (t & 3) * 16;
    const float* ip = in + (ll)(r0 + tr) * 256 + c0 + tc;
    #pragma unroll
    for (int i = 0; i < 4; ++i) {
        float4 v = *(const float4*)(ip + i * 4);
        tile[tr][tc + i * 4 + 0] = v.x;
        tile[tr][tc + i * 4 + 1] = v.y;
        tile[tr][tc + i * 4 + 2] = v.z;
        tile[tr][tc + i * 4 + 3] = v.w;
    }
    __syncthreads();
    int cl = t >> 2, rl = (t & 3) * 16;
    ushort* op = out + (ll)(c0 + cl) * 256 + r0 + rl;
    #pragma unroll
    for (int i = 0; i < 16; ++i) op[i] = f2bf(tile[rl + i][cl]);
}

__global__ __launch_bounds__(256)
void btext_fill(const float* __restrict__ wlK, const float* __restrict__ wlV,
                ushort* __restrict__ btExt)
{
    int idx = blockIdx.x * 256 + threadIdx.x;
    int n = idx >> 6, j = idx & 63;
    ushort v = 0;
    if (j < 40) {
        int hp = j / 10, c = j - hp * 10;
        int nn = n & 1023;
        int h = nn >> 8, d = nn & 255;
        if (hp == h) {
            const float* wl = (n >= 1024) ? wlV : wlK;
            v = f2bf(wl[c * 256 + d]);
        }
    }
    btExt[(ll)n * 1088 + 1024 + j] = v;
}

extern "C" void kernel_launch(void* const* d_in, const int* in_sizes, int n_in,
                              void* d_out, int out_size, void* d_ws, size_t ws_size,
                              hipStream_t stream)
{
    (void)in_sizes; (void)n_in; (void)out_size; (void)ws_size;

    const float* query = (const float*)d_in[0];
    const float* value = (const float*)d_in[1];
    const float* prev  = (const float*)d_in[2];
    const float* convw = (const float*)d_in[3];
    const float* convb = (const float*)d_in[4];
    const float* Wq    = (const float*)d_in[5];
    const float* bq    = (const float*)d_in[6];
    const float* Wv    = (const float*)d_in[7];
    const float* Wloc  = (const float*)d_in[8];
    const float* bias  = (const float*)d_in[9];
    const float* Wout  = (const float*)d_in[10];
    const float* bout  = (const float*)d_in[11];
    const float* swq   = (const float*)d_in[12];
    const float* sbq   = (const float*)d_in[13];
    const float* swk   = (const float*)d_in[14];
    const float* sbk   = (const float*)d_in[15];
    const float* swv   = (const float*)d_in[16];
    const float* sbv   = (const float*)d_in[17];

    float* out_buf  = (float*)d_out;                          // (B,QL,HID) f32
    float* attn_buf = out_buf + (ll)B_ * QL_ * HID_;          // (64,512,512) f32

    // ---- workspace layout, BYTE offsets (liveness-audited, total 146.44 MB) ----
    char* wsb = (char*)d_ws;
    ushort* vext   = (ushort*)(wsb + 0);           // 8192x1088 bf16 -> dead after kkvv
    ushort* WoutTb = (ushort*)(wsb + 0);           // 1024x2048 bf16 (after kkvv)
    ushort* kkb    = (ushort*)(wsb + 17825792);    // 8192x1024 bf16
    ushort* attnb  = (ushort*)(wsb + 34603008);    // 64*512*512 bf16
    ushort* Acat   = (ushort*)(wsb + 68157440);    // 8192x2048 bf16 (ctx | query)
    ushort* qqb    = (ushort*)(wsb + 101711872);   // 8192x1024 bf16
    ushort* vvT_b  = (ushort*)(wsb + 118489088);   // 1024x8192 bf16
    float*  bqq    = (float*)(wsb + 135266304);
    float*  bkv    = (float*)(wsb + 135270400);
    float*  wlK    = (float*)(wsb + 135278592);
    float*  wlV    = (float*)(wsb + 135288832);
    ushort* swqTb  = (ushort*)(wsb + 135299072);   // 256x256 bf16 (swk/swv contiguous)
    ushort* swkTb  = (ushort*)(wsb + 135430144);
    ushort* swvTb  = (ushort*)(wsb + 135561216);
    ushort* Wqb    = (ushort*)(wsb + 135692288);
    ushort* Wvb    = (ushort*)(wsb + 137789440);
    ushort* wqqTb  = (ushort*)(wsb + 139886592);
    ushort* btExt  = (ushort*)(wsb + 141983744);

    // --- merged precomputes (input-only deps) ---
    prep_acts<<<18432, 256, 0, stream>>>(query, value, prev, convw, convb, Acat + 1024, vext);
    prep_w<<<2080, 256, 0, stream>>>(Wq, Wv, Wqb, Wvb, bq, sbq, swq, bias, sbk, swk,
                                     sbv, swv, Wloc, bqq, bkv, wlK, wlV);
    sw3_transpose<<<dim3(4, 4, 3), 256, 0, stream>>>(swq, swk, swv, swqTb, swkTb, swvTb);

    // folded weights via MFMA: wqqT, and [swk|swv] x Wv batched in ONE dispatch
    gemm_bf16<<<dim3(8, 2, 4), 256, 0, stream>>>(swqTb, Wqb, wqqTb, nullptr, nullptr,
        256, 256, 1024, 1024, 0, 0, 0, 256, 0, 262144, 1, 1.0f, 1);
    gemm_bf16<<<dim3(8, 2, 8), 256, 0, stream>>>(swkTb, Wvb, btExt, nullptr, nullptr,
        256, 256, 1024, 1088, 0, 65536, 256, 0, 278528, 1114112, 4, 1.0f, 1);
    btext_fill<<<512, 256, 0, stream>>>(wlK, wlV, btExt);

    // qq = (query @ Wqq + bqq) / 16 -> bf16   [gemm32]
    gemm32<<<dim3(8, 64), 256, 0, stream>>>(Acat + 1024, wqqTb, qqb, nullptr, bqq,
        1024, 2048, 1024, 1024, 0.0625f, 1);

    // kk|vv = [value|conv] @ [Wvk;wlK | Wvv;wlV] + bkv; kk->kkb, vv->vvT   [gemm32]
    gemm32<<<dim3(16, 64), 256, 0, stream>>>(vext, btExt, kkb, vvT_b, bkv,
        1088, 1088, 1088, 1024, 1.0f, 1 | 8);

    // Wout^T bf16 into region A (vext dead after kkvv)
    transpose_cast<<<dim3(16, 32), 256, 0, stream>>>(Wout, WoutTb, 2048, 1024, 2048);

    // fused scores + softmax: attn f32 -> d_out, bf16 copy -> attnb
    scores_softmax<<<dim3(1, 4, 64), 512, 0, stream>>>(qqb, kkb, attn_buf, attnb);

    // ctx = attn @ vv -> bf16 into Acat left half (merged heads)
    gemm_bf16<<<dim3(2, 4, 64), 256, 0, stream>>>(attnb, vvT_b, Acat, nullptr, nullptr,
        512, 512, 8192, 2048,
        262144, 4194304, 512, 2097152, 1048576, 256, 16, 1.0f, 1);

    // out = tanh([ctx | query] @ Wout + bout) -> f32   [gemm32]
    gemm32<<<dim3(8, 64), 256, 0, stream>>>(Acat, WoutTb, out_buf, nullptr, bout,
        2048, 2048, 2048, 1024, 1.0f, 2);
}

// Round 14
// 261.803 us; speedup vs baseline: 1.0760x; 1.0760x over previous
//
#include <hip/hip_runtime.h>
#include <math.h>

// Problem constants
#define B_   16
#define QL_  512
#define VL_  512
#define HID_ 1024
#define NH_  4
#define CH_  10
#define DIM_ 256

typedef __attribute__((ext_vector_type(4))) float f32x4;
typedef __attribute__((ext_vector_type(8))) short bf16x8;
typedef long long ll;

__device__ __forceinline__ ushort f2bf(float f) {
    union { float f; uint32_t u; } c; c.f = f;
    uint32_t u = c.u;
    u += 0x7fffu + ((u >> 16) & 1u);
    return (ushort)(u >> 16);
}

__device__ __forceinline__ void gload16(const void* g, void* l) {
    __builtin_amdgcn_global_load_lds((const __attribute__((address_space(1))) void*)g,
                                     (__attribute__((address_space(3))) void*)l,
                                     16, 0, 0);
}

// ============ gemm_bf16: 128x128, BK=64 dbuf, counted-vmcnt (best measured: R9/R12) ============
// C = op((A @ Bt^T) + bias) * scale. A: M x K bf16 (lda). Bt: N x K bf16 (ldb).
// flags: 1 = bf16 C, 2 = tanh, 8 = kkvv split (cols>=1024 -> Cv2 transposed, ld 8192).
// Loop: stage(t+1) -> vmcnt(8) [tile t's own loads done; t+1's stay in flight]
//       -> s_barrier [all waves have tile t] -> MFMA(t) -> s_barrier [reads done].
__global__ __launch_bounds__(256)
void gemm_bf16(const ushort* __restrict__ A, const ushort* __restrict__ Bt,
               void* __restrict__ Cv, void* __restrict__ Cv2,
               const float* __restrict__ bias,
               int K, int lda, int ldb, int ldc,
               long long a1, long long a2, long long b1, long long b2,
               long long c1, long long c2, int WB,
               float post_scale, int flags)
{
    __shared__ ushort As[2][128 * 64];
    __shared__ ushort Bs[2][128 * 64];

    int z = blockIdx.z;
    int zm = z % WB, zd = z / WB;
    A  += a1 * zm + a2 * zd;
    Bt += b1 * zm + b2 * zd;
    long long coff = c1 * (long long)zm + c2 * (long long)zd;

    int gx = gridDim.x;
    int nwg = gx * gridDim.y;
    int flat = blockIdx.y * gx + blockIdx.x;
    int q = nwg >> 3, r = nwg & 7;
    int xcd = flat & 7, idx = flat >> 3;
    int logical = (xcd < r ? xcd * (q + 1) : r * (q + 1) + (xcd - r) * q) + idx;
    int brow = (logical / gx) * 128;
    int bcol = (logical % gx) * 128;

    int t = threadIdx.x;
    int lane = t & 63, w = t >> 6;
    int wr = (w >> 1) * 64, wc = (w & 1) * 64;

    int srow  = t >> 3;
    int sslot = t & 7;
    int sk = ((sslot ^ (srow & 7)) << 3);
    const ushort* gaBase = A  + (long long)(brow + srow) * lda + sk;
    const ushort* gbBase = Bt + (long long)(bcol + srow) * ldb + sk;

    f32x4 acc[4][4] = {};

    auto stage = [&](int buf, int k0) {
        ushort* la = &As[buf][t * 8];
        ushort* lb = &Bs[buf][t * 8];
        #pragma unroll
        for (int i = 0; i < 4; ++i) {
            gload16(gaBase + (long long)(i * 32) * lda + k0, la + i * 2048);
            gload16(gbBase + (long long)(i * 32) * ldb + k0, lb + i * 2048);
        }
    };

    int NT = K >> 6;
    stage(0, 0);
    int cur = 0;
    for (int tI = 0; tI < NT; ++tI) {
        if (tI + 1 < NT) {
            stage(cur ^ 1, (tI + 1) << 6);
            asm volatile("s_waitcnt vmcnt(8)" ::: "memory");
        } else {
            asm volatile("s_waitcnt vmcnt(0)" ::: "memory");
        }
        __builtin_amdgcn_s_barrier();
        __builtin_amdgcn_sched_barrier(0);

        #pragma unroll
        for (int kk = 0; kk < 2; ++kk) {
            int slot = ((kk << 2) + (lane >> 4)) ^ (lane & 7);
            const ushort* ab = &As[cur][(wr + (lane & 15)) * 64 + slot * 8];
            const ushort* bb = &Bs[cur][(wc + (lane & 15)) * 64 + slot * 8];
            bf16x8 af[4], bfr[4];
            #pragma unroll
            for (int m = 0; m < 4; ++m) af[m]  = *(const bf16x8*)(ab + m * 1024);
            #pragma unroll
            for (int n = 0; n < 4; ++n) bfr[n] = *(const bf16x8*)(bb + n * 1024);
            #pragma unroll
            for (int m = 0; m < 4; ++m)
                #pragma unroll
                for (int n = 0; n < 4; ++n)
                    acc[m][n] = __builtin_amdgcn_mfma_f32_16x16x32_bf16(af[m], bfr[n], acc[m][n], 0, 0, 0);
        }

        __builtin_amdgcn_s_barrier();
        __builtin_amdgcn_sched_barrier(0);
        cur ^= 1;
    }

    float*  Cf = (float*)Cv + coff;
    ushort* Cb = (ushort*)Cv + coff;
    ushort* C2 = (ushort*)Cv2;
    #pragma unroll
    for (int m = 0; m < 4; ++m) {
        int r0 = brow + wr + m * 16 + (lane >> 4) * 4;
        #pragma unroll
        for (int n = 0; n < 4; ++n) {
            int c = bcol + wc + n * 16 + (lane & 15);
            float bv = bias ? bias[c] : 0.0f;
            float v0 = (acc[m][n][0] + bv) * post_scale;
            float v1 = (acc[m][n][1] + bv) * post_scale;
            float v2 = (acc[m][n][2] + bv) * post_scale;
            float v3 = (acc[m][n][3] + bv) * post_scale;
            if (flags & 2) { v0 = tanhf(v0); v1 = tanhf(v1); v2 = tanhf(v2); v3 = tanhf(v3); }
            if ((flags & 8) && c >= 1024) {
                ushort4 o;
                o.x = f2bf(v0); o.y = f2bf(v1); o.z = f2bf(v2); o.w = f2bf(v3);
                *(ushort4*)&C2[(long long)(c - 1024) * 8192 + r0] = o;
            } else if (flags & 1) {
                Cb[(long long)(r0 + 0) * ldc + c] = f2bf(v0);
                Cb[(long long)(r0 + 1) * ldc + c] = f2bf(v1);
                Cb[(long long)(r0 + 2) * ldc + c] = f2bf(v2);
                Cb[(long long)(r0 + 3) * ldc + c] = f2bf(v3);
            } else {
                Cf[(long long)(r0 + 0) * ldc + c] = v0;
                Cf[(long long)(r0 + 1) * ldc + c] = v1;
                Cf[(long long)(r0 + 2) * ldc + c] = v2;
                Cf[(long long)(r0 + 3) * ldc + c] = v3;
            }
        }
    }
}

// ======= fused scores + softmax, BK=32 dbuf + counted vmcnt (R12-proven) ==========
__global__ __launch_bounds__(512, 1)
void scores_softmax(const ushort* __restrict__ qq, const ushort* __restrict__ kk,
                    float* __restrict__ attn, ushort* __restrict__ attnb)
{
    __shared__ ushort As[2][128 * 32];
    __shared__ ushort Bs[2][512 * 32];
    __shared__ float redm[4][128];
    __shared__ float reds[4][128];

    int z = blockIdx.z;              // n = h*16 + b
    int b = z & 15, h = z >> 4;
    const ushort* Abase = qq + (ll)b * 524288 + h * 256;
    const ushort* Bbase = kk + (ll)b * 524288 + h * 256;
    float*  aout = attn  + (ll)z * 262144;
    ushort* bout = attnb + (ll)z * 262144;

    int brow = blockIdx.y * 128;

    int t = threadIdx.x;
    int lane = t & 63, w = t >> 6;
    int wr = (w >> 2) * 64;
    int wc = (w & 3) * 128;

    int srow = t >> 2, sslot = t & 3;
    int sk = ((sslot ^ ((srow >> 1) & 3)) << 3);
    const ushort* ga = Abase + (ll)(brow + srow) * 1024 + sk;
    const ushort* gb = Bbase + (ll)srow * 1024 + sk;

    f32x4 acc[4][8] = {};

    auto stage = [&](int buf, int k0) {
        gload16(ga + k0, &As[buf][t * 8]);
        #pragma unroll
        for (int i = 0; i < 4; ++i)
            gload16(gb + (ll)(i * 128) * 1024 + k0, &Bs[buf][t * 8 + i * 4096]);
    };

    int cur = 0;
    stage(0, 0);
    #pragma unroll
    for (int tI = 0; tI < 8; ++tI) {
        if (tI + 1 < 8) {
            stage(cur ^ 1, (tI + 1) << 5);
            asm volatile("s_waitcnt vmcnt(5)" ::: "memory");
        } else {
            asm volatile("s_waitcnt vmcnt(0)" ::: "memory");
        }
        __builtin_amdgcn_s_barrier();
        __builtin_amdgcn_sched_barrier(0);

        int slot = (lane >> 4) ^ ((lane >> 1) & 3);
        const ushort* ab = &As[cur][(wr + (lane & 15)) * 32 + slot * 8];
        const ushort* bb = &Bs[cur][(wc + (lane & 15)) * 32 + slot * 8];
        bf16x8 af[4], bfr[8];
        #pragma unroll
        for (int m = 0; m < 4; ++m) af[m]  = *(const bf16x8*)(ab + m * 512);
        #pragma unroll
        for (int n = 0; n < 8; ++n) bfr[n] = *(const bf16x8*)(bb + n * 512);
        #pragma unroll
        for (int m = 0; m < 4; ++m)
            #pragma unroll
            for (int n = 0; n < 8; ++n)
                acc[m][n] = __builtin_amdgcn_mfma_f32_16x16x32_bf16(af[m], bfr[n], acc[m][n], 0, 0, 0);

        __builtin_amdgcn_s_barrier();
        __builtin_amdgcn_sched_barrier(0);
        cur ^= 1;
    }

    float rmax[4][4], rinv[4][4];
    #pragma unroll
    for (int m = 0; m < 4; ++m)
        #pragma unroll
        for (int j = 0; j < 4; ++j) {
            float pm = acc[m][0][j];
            #pragma unroll
            for (int n = 1; n < 8; ++n) pm = fmaxf(pm, acc[m][n][j]);
            pm = fmaxf(pm, __shfl_xor(pm, 1));
            pm = fmaxf(pm, __shfl_xor(pm, 2));
            pm = fmaxf(pm, __shfl_xor(pm, 4));
            pm = fmaxf(pm, __shfl_xor(pm, 8));
            if ((lane & 15) == 0)
                redm[w & 3][wr + m * 16 + (lane >> 4) * 4 + j] = pm;
        }
    __syncthreads();
    #pragma unroll
    for (int m = 0; m < 4; ++m)
        #pragma unroll
        for (int j = 0; j < 4; ++j) {
            int row = wr + m * 16 + (lane >> 4) * 4 + j;
            rmax[m][j] = fmaxf(fmaxf(redm[0][row], redm[1][row]),
                               fmaxf(redm[2][row], redm[3][row]));
        }
    #pragma unroll
    for (int m = 0; m < 4; ++m)
        #pragma unroll
        for (int j = 0; j < 4; ++j) {
            float ps = 0.f;
            #pragma unroll
            for (int n = 0; n < 8; ++n) {
                float e = __expf(acc[m][n][j] - rmax[m][j]);
                acc[m][n][j] = e;
                ps += e;
            }
            ps += __shfl_xor(ps, 1);
            ps += __shfl_xor(ps, 2);
            ps += __shfl_xor(ps, 4);
            ps += __shfl_xor(ps, 8);
            if ((lane & 15) == 0)
                reds[w & 3][wr + m * 16 + (lane >> 4) * 4 + j] = ps;
        }
    __syncthreads();
    #pragma unroll
    for (int m = 0; m < 4; ++m)
        #pragma unroll
        for (int j = 0; j < 4; ++j) {
            int row = wr + m * 16 + (lane >> 4) * 4 + j;
            rinv[m][j] = 1.0f / (reds[0][row] + reds[1][row] + reds[2][row] + reds[3][row]);
        }
    #pragma unroll
    for (int m = 0; m < 4; ++m) {
        int r0 = brow + wr + m * 16 + (lane >> 4) * 4;
        #pragma unroll
        for (int n = 0; n < 8; ++n) {
            int c = wc + n * 16 + (lane & 15);
            #pragma unroll
            for (int j = 0; j < 4; ++j) {
                float v = acc[m][n][j] * rinv[m][j];
                aout[(ll)(r0 + j) * 512 + c] = v;
                bout[(ll)(r0 + j) * 512 + c] = f2bf(v);
            }
        }
    }
}

// ================= merged prep kernels =================
__global__ __launch_bounds__(256)
void prep_acts(const float* __restrict__ query, const float* __restrict__ value,
               const float* __restrict__ prev, const float* __restrict__ cw,
               const float* __restrict__ cb,
               ushort* __restrict__ Acat, ushort* __restrict__ vext)
{
    int bI = blockIdx.x;
    if (bI < 16384) {
        const float* in = (bI < 8192) ? query : value;
        ushort* out = (bI < 8192) ? Acat : vext;
        int ld_out = (bI < 8192) ? 2048 : 1088;
        ll idx = (ll)(bI & 8191) * 256 + threadIdx.x;
        ll row = idx >> 8;
        int c4 = (int)(idx & 255) * 4;
        float4 v = *(const float4*)&in[row * 1024 + c4];
        ushort4 o;
        o.x = f2bf(v.x); o.y = f2bf(v.y); o.z = f2bf(v.z); o.w = f2bf(v.w);
        *(ushort4*)&out[row * ld_out + c4] = o;
    } else {
        int idx = (bI - 16384) * 256 + threadIdx.x;
        int row = idx >> 6, j = idx & 63;
        int b = row >> 9, l = row & 511;
        ushort v = 0;
        if (j < 40) {
            int h = j / 10, c = j - h * 10;
            const float* p = prev + (ll)(b * 4 + h) * VL_;
            float xm = (l > 0)       ? p[l - 1] : 0.f;
            float x0 = p[l];
            float xp = (l < VL_ - 1) ? p[l + 1] : 0.f;
            v = f2bf(xm * cw[c * 3 + 0] + x0 * cw[c * 3 + 1] + xp * cw[c * 3 + 2] + cb[c]);
        }
        vext[(ll)row * 1088 + 1024 + j] = v;
    }
}

__global__ __launch_bounds__(256)
void prep_w(const float* __restrict__ Wq, const float* __restrict__ Wv,
            ushort* __restrict__ Wqb, ushort* __restrict__ Wvb,
            const float* __restrict__ bq, const float* __restrict__ sbq, const float* __restrict__ swq,
            const float* __restrict__ bias, const float* __restrict__ sbk, const float* __restrict__ swk,
            const float* __restrict__ sbv, const float* __restrict__ swv,
            const float* __restrict__ Wloc,
            float* __restrict__ bqq, float* __restrict__ bkv,
            float* __restrict__ wlK, float* __restrict__ wlV)
{
    int bI = blockIdx.x;
    if (bI < 2048) {
        const float* in = (bI < 1024) ? Wq : Wv;
        ushort* out = (bI < 1024) ? Wqb : Wvb;
        ll idx = (ll)(bI & 1023) * 256 + threadIdx.x;
        ll row = idx >> 8;
        int c4 = (int)(idx & 255) * 4;
        float4 v = *(const float4*)&in[row * 1024 + c4];
        ushort4 o;
        o.x = f2bf(v.x); o.y = f2bf(v.y); o.z = f2bf(v.z); o.w = f2bf(v.w);
        *(ushort4*)&out[row * 1024 + c4] = o;
        return;
    }
    int idx = (bI - 2048) * 256 + threadIdx.x;
    if (idx < 1024) {
        int h = idx >> 8, d = idx & 255;
        float s = 0.f;
        for (int j = 0; j < 256; ++j) s += bq[h * 256 + j] * swq[j * 256 + d];
        bqq[idx] = s + sbq[d];
    } else if (idx < 3072) {
        int i = idx - 1024;
        int kv = i >> 10, ii = i & 1023;
        int h = ii >> 8, d = ii & 255;
        const float* sw = kv ? swv : swk;
        const float* sb = kv ? sbv : sbk;
        float s = 0.f;
        for (int j = 0; j < 256; ++j) s += bias[h * 256 + j] * sw[j * 256 + d];
        bkv[i] = s + sb[d];
    } else if (idx < 5632) {
        int i = idx - 3072; int c = i >> 8, d = i & 255;
        float s = 0.f;
        for (int j = 0; j < 256; ++j) s += Wloc[c * 256 + j] * swk[j * 256 + d];
        wlK[i] = s;
    } else if (idx < 8192) {
        int i = idx - 5632; int c = i >> 8, d = i & 255;
        float s = 0.f;
        for (int j = 0; j < 256; ++j) s += Wloc[c * 256 + j] * swv[j * 256 + d];
        wlV[i] = s;
    }
}

__global__ __launch_bounds__(256)
void transpose_cast(const float* __restrict__ in, ushort* __restrict__ out, int R, int C, int ld_out)
{
    __shared__ float tile[64][65];
    int r0 = blockIdx.y * 64, c0 = blockIdx.x * 64;
    int t = threadIdx.x;
    int tr = t >> 2, tc = (t & 3) * 16;
    const float* ip = in + (ll)(r0 + tr) * C + c0 + tc;
    #pragma unroll
    for (int i = 0; i < 4; ++i) {
        float4 v = *(const float4*)(ip + i * 4);
        tile[tr][tc + i * 4 + 0] = v.x;
        tile[tr][tc + i * 4 + 1] = v.y;
        tile[tr][tc + i * 4 + 2] = v.z;
        tile[tr][tc + i * 4 + 3] = v.w;
    }
    __syncthreads();
    int cl = t >> 2, rl = (t & 3) * 16;
    ushort* op = out + (ll)(c0 + cl) * ld_out + r0 + rl;
    #pragma unroll
    for (int i = 0; i < 16; ++i) op[i] = f2bf(tile[rl + i][cl]);
}

__global__ __launch_bounds__(256)
void sw3_transpose(const float* __restrict__ swq, const float* __restrict__ swk,
                   const float* __restrict__ swv, ushort* __restrict__ oq,
                   ushort* __restrict__ ok, ushort* __restrict__ ov)
{
    __shared__ float tile[64][65];
    const float* in = (blockIdx.z == 0) ? swq : (blockIdx.z == 1) ? swk : swv;
    ushort* out     = (blockIdx.z == 0) ? oq  : (blockIdx.z == 1) ? ok  : ov;
    int r0 = blockIdx.y * 64, c0 = blockIdx.x * 64;
    int t = threadIdx.x;
    int tr = t >> 2, tc = (t & 3) * 16;
    const float* ip = in + (ll)(r0 + tr) * 256 + c0 + tc;
    #pragma unroll
    for (int i = 0; i < 4; ++i) {
        float4 v = *(const float4*)(ip + i * 4);
        tile[tr][tc + i * 4 + 0] = v.x;
        tile[tr][tc + i * 4 + 1] = v.y;
        tile[tr][tc + i * 4 + 2] = v.z;
        tile[tr][tc + i * 4 + 3] = v.w;
    }
    __syncthreads();
    int cl = t >> 2, rl = (t & 3) * 16;
    ushort* op = out + (ll)(c0 + cl) * 256 + r0 + rl;
    #pragma unroll
    for (int i = 0; i < 16; ++i) op[i] = f2bf(tile[rl + i][cl]);
}

__global__ __launch_bounds__(256)
void btext_fill(const float* __restrict__ wlK, const float* __restrict__ wlV,
                ushort* __restrict__ btExt)
{
    int idx = blockIdx.x * 256 + threadIdx.x;
    int n = idx >> 6, j = idx & 63;
    ushort v = 0;
    if (j < 40) {
        int hp = j / 10, c = j - hp * 10;
        int nn = n & 1023;
        int h = nn >> 8, d = nn & 255;
        if (hp == h) {
            const float* wl = (n >= 1024) ? wlV : wlK;
            v = f2bf(wl[c * 256 + d]);
        }
    }
    btExt[(ll)n * 1088 + 1024 + j] = v;
}

extern "C" void kernel_launch(void* const* d_in, const int* in_sizes, int n_in,
                              void* d_out, int out_size, void* d_ws, size_t ws_size,
                              hipStream_t stream)
{
    (void)in_sizes; (void)n_in; (void)out_size; (void)ws_size;

    const float* query = (const float*)d_in[0];
    const float* value = (const float*)d_in[1];
    const float* prev  = (const float*)d_in[2];
    const float* convw = (const float*)d_in[3];
    const float* convb = (const float*)d_in[4];
    const float* Wq    = (const float*)d_in[5];
    const float* bq    = (const float*)d_in[6];
    const float* Wv    = (const float*)d_in[7];
    const float* Wloc  = (const float*)d_in[8];
    const float* bias  = (const float*)d_in[9];
    const float* Wout  = (const float*)d_in[10];
    const float* bout  = (const float*)d_in[11];
    const float* swq   = (const float*)d_in[12];
    const float* sbq   = (const float*)d_in[13];
    const float* swk   = (const float*)d_in[14];
    const float* sbk   = (const float*)d_in[15];
    const float* swv   = (const float*)d_in[16];
    const float* sbv   = (const float*)d_in[17];

    float* out_buf  = (float*)d_out;                          // (B,QL,HID) f32
    float* attn_buf = out_buf + (ll)B_ * QL_ * HID_;          // (64,512,512) f32

    // ---- workspace layout, BYTE offsets (liveness-audited, total 146.44 MB) ----
    char* wsb = (char*)d_ws;
    ushort* vext   = (ushort*)(wsb + 0);           // 8192x1088 bf16 -> dead after kkvv
    ushort* WoutTb = (ushort*)(wsb + 0);           // 1024x2048 bf16 (after kkvv)
    ushort* kkb    = (ushort*)(wsb + 17825792);    // 8192x1024 bf16
    ushort* attnb  = (ushort*)(wsb + 34603008);    // 64*512*512 bf16
    ushort* Acat   = (ushort*)(wsb + 68157440);    // 8192x2048 bf16 (ctx | query)
    ushort* qqb    = (ushort*)(wsb + 101711872);   // 8192x1024 bf16
    ushort* vvT_b  = (ushort*)(wsb + 118489088);   // 1024x8192 bf16
    float*  bqq    = (float*)(wsb + 135266304);
    float*  bkv    = (float*)(wsb + 135270400);
    float*  wlK    = (float*)(wsb + 135278592);
    float*  wlV    = (float*)(wsb + 135288832);
    ushort* swqTb  = (ushort*)(wsb + 135299072);   // 256x256 bf16 (swk/swv contiguous)
    ushort* swkTb  = (ushort*)(wsb + 135430144);
    ushort* swvTb  = (ushort*)(wsb + 135561216);
    ushort* Wqb    = (ushort*)(wsb + 135692288);
    ushort* Wvb    = (ushort*)(wsb + 137789440);
    ushort* wqqTb  = (ushort*)(wsb + 139886592);
    ushort* btExt  = (ushort*)(wsb + 141983744);

    // --- merged precomputes (input-only deps) ---
    prep_acts<<<18432, 256, 0, stream>>>(query, value, prev, convw, convb, Acat + 1024, vext);
    prep_w<<<2080, 256, 0, stream>>>(Wq, Wv, Wqb, Wvb, bq, sbq, swq, bias, sbk, swk,
                                     sbv, swv, Wloc, bqq, bkv, wlK, wlV);
    sw3_transpose<<<dim3(4, 4, 3), 256, 0, stream>>>(swq, swk, swv, swqTb, swkTb, swvTb);

    // folded weights via MFMA: wqqT, and [swk|swv] x Wv batched in ONE dispatch
    gemm_bf16<<<dim3(8, 2, 4), 256, 0, stream>>>(swqTb, Wqb, wqqTb, nullptr, nullptr,
        256, 256, 1024, 1024, 0, 0, 0, 256, 0, 262144, 1, 1.0f, 1);
    gemm_bf16<<<dim3(8, 2, 8), 256, 0, stream>>>(swkTb, Wvb, btExt, nullptr, nullptr,
        256, 256, 1024, 1088, 0, 65536, 256, 0, 278528, 1114112, 4, 1.0f, 1);
    btext_fill<<<512, 256, 0, stream>>>(wlK, wlV, btExt);

    // qq = (query @ Wqq + bqq) / 16 -> bf16
    gemm_bf16<<<dim3(8, 64, 1), 256, 0, stream>>>(Acat + 1024, wqqTb, qqb, nullptr, bqq,
        1024, 2048, 1024, 1024, 0, 0, 0, 0, 0, 0, 1, 0.0625f, 1);

    // kk|vv = [value|conv] @ [Wvk;wlK | Wvv;wlV] + bkv; kk->kkb, vv->vvT (transposed)
    gemm_bf16<<<dim3(16, 64, 1), 256, 0, stream>>>(vext, btExt, kkb, vvT_b, bkv,
        1088, 1088, 1088, 1024, 0, 0, 0, 0, 0, 0, 1, 1.0f, 1 | 8);

    // Wout^T bf16 into region A (vext dead after kkvv)
    transpose_cast<<<dim3(16, 32), 256, 0, stream>>>(Wout, WoutTb, 2048, 1024, 2048);

    // fused scores + softmax: attn f32 -> d_out, bf16 copy -> attnb
    scores_softmax<<<dim3(1, 4, 64), 512, 0, stream>>>(qqb, kkb, attn_buf, attnb);

    // ctx = attn @ vv -> bf16 into Acat left half (merged heads)
    gemm_bf16<<<dim3(2, 4, 64), 256, 0, stream>>>(attnb, vvT_b, Acat, nullptr, nullptr,
        512, 512, 8192, 2048,
        262144, 4194304, 512, 2097152, 1048576, 256, 16, 1.0f, 1);

    // out = tanh([ctx | query] @ Wout + bout) -> f32
    gemm_bf16<<<dim3(8, 64, 1), 256, 0, stream>>>(Acat, WoutTb, out_buf, nullptr, bout,
        2048, 2048, 2048, 1024, 0, 0, 0, 0, 0, 0, 1, 1.0f, 2);
}

// Round 15
// 255.831 us; speedup vs baseline: 1.1011x; 1.0233x over previous
//
#include <hip/hip_runtime.h>
#include <math.h>

// Problem constants
#define B_   16
#define QL_  512
#define VL_  512
#define HID_ 1024
#define NH_  4
#define CH_  10
#define DIM_ 256

typedef __attribute__((ext_vector_type(4))) float f32x4;
typedef __attribute__((ext_vector_type(8))) short bf16x8;
typedef long long ll;

__device__ __forceinline__ ushort f2bf(float f) {
    union { float f; uint32_t u; } c; c.f = f;
    uint32_t u = c.u;
    u += 0x7fffu + ((u >> 16) & 1u);
    return (ushort)(u >> 16);
}

__device__ __forceinline__ void gload16(const void* g, void* l) {
    __builtin_amdgcn_global_load_lds((const __attribute__((address_space(1))) void*)g,
                                     (__attribute__((address_space(3))) void*)l,
                                     16, 0, 0);
}

// ============ gemm_bf16: 128x128, BK=64 dbuf, counted-vmcnt (best measured: R9/R12) ============
// C = op((A @ Bt^T) + bias) * scale. A: M x K bf16 (lda). Bt: N x K bf16 (ldb).
// flags: 1 = bf16 C, 2 = tanh, 8 = kkvv split (cols>=1024 -> Cv2 transposed, ld 8192).
// Loop: stage(t+1) -> vmcnt(8) [tile t's own loads done; t+1's stay in flight]
//       -> s_barrier [all waves have tile t] -> MFMA(t) -> s_barrier [reads done].
__global__ __launch_bounds__(256)
void gemm_bf16(const ushort* __restrict__ A, const ushort* __restrict__ Bt,
               void* __restrict__ Cv, void* __restrict__ Cv2,
               const float* __restrict__ bias,
               int K, int lda, int ldb, int ldc,
               long long a1, long long a2, long long b1, long long b2,
               long long c1, long long c2, int WB,
               float post_scale, int flags)
{
    __shared__ ushort As[2][128 * 64];
    __shared__ ushort Bs[2][128 * 64];

    int z = blockIdx.z;
    int zm = z % WB, zd = z / WB;
    A  += a1 * zm + a2 * zd;
    Bt += b1 * zm + b2 * zd;
    long long coff = c1 * (long long)zm + c2 * (long long)zd;

    int gx = gridDim.x;
    int nwg = gx * gridDim.y;
    int flat = blockIdx.y * gx + blockIdx.x;
    int q = nwg >> 3, r = nwg & 7;
    int xcd = flat & 7, idx = flat >> 3;
    int logical = (xcd < r ? xcd * (q + 1) : r * (q + 1) + (xcd - r) * q) + idx;
    int brow = (logical / gx) * 128;
    int bcol = (logical % gx) * 128;

    int t = threadIdx.x;
    int lane = t & 63, w = t >> 6;
    int wr = (w >> 1) * 64, wc = (w & 1) * 64;

    int srow  = t >> 3;
    int sslot = t & 7;
    int sk = ((sslot ^ (srow & 7)) << 3);
    const ushort* gaBase = A  + (long long)(brow + srow) * lda + sk;
    const ushort* gbBase = Bt + (long long)(bcol + srow) * ldb + sk;

    f32x4 acc[4][4] = {};

    auto stage = [&](int buf, int k0) {
        ushort* la = &As[buf][t * 8];
        ushort* lb = &Bs[buf][t * 8];
        #pragma unroll
        for (int i = 0; i < 4; ++i) {
            gload16(gaBase + (long long)(i * 32) * lda + k0, la + i * 2048);
            gload16(gbBase + (long long)(i * 32) * ldb + k0, lb + i * 2048);
        }
    };

    int NT = K >> 6;
    stage(0, 0);
    int cur = 0;
    for (int tI = 0; tI < NT; ++tI) {
        if (tI + 1 < NT) {
            stage(cur ^ 1, (tI + 1) << 6);
            asm volatile("s_waitcnt vmcnt(8)" ::: "memory");
        } else {
            asm volatile("s_waitcnt vmcnt(0)" ::: "memory");
        }
        __builtin_amdgcn_s_barrier();
        __builtin_amdgcn_sched_barrier(0);

        #pragma unroll
        for (int kk = 0; kk < 2; ++kk) {
            int slot = ((kk << 2) + (lane >> 4)) ^ (lane & 7);
            const ushort* ab = &As[cur][(wr + (lane & 15)) * 64 + slot * 8];
            const ushort* bb = &Bs[cur][(wc + (lane & 15)) * 64 + slot * 8];
            bf16x8 af[4], bfr[4];
            #pragma unroll
            for (int m = 0; m < 4; ++m) af[m]  = *(const bf16x8*)(ab + m * 1024);
            #pragma unroll
            for (int n = 0; n < 4; ++n) bfr[n] = *(const bf16x8*)(bb + n * 1024);
            #pragma unroll
            for (int m = 0; m < 4; ++m)
                #pragma unroll
                for (int n = 0; n < 4; ++n)
                    acc[m][n] = __builtin_amdgcn_mfma_f32_16x16x32_bf16(af[m], bfr[n], acc[m][n], 0, 0, 0);
        }

        __builtin_amdgcn_s_barrier();
        __builtin_amdgcn_sched_barrier(0);
        cur ^= 1;
    }

    float*  Cf = (float*)Cv + coff;
    ushort* Cb = (ushort*)Cv + coff;
    ushort* C2 = (ushort*)Cv2;
    #pragma unroll
    for (int m = 0; m < 4; ++m) {
        int r0 = brow + wr + m * 16 + (lane >> 4) * 4;
        #pragma unroll
        for (int n = 0; n < 4; ++n) {
            int c = bcol + wc + n * 16 + (lane & 15);
            float bv = bias ? bias[c] : 0.0f;
            float v0 = (acc[m][n][0] + bv) * post_scale;
            float v1 = (acc[m][n][1] + bv) * post_scale;
            float v2 = (acc[m][n][2] + bv) * post_scale;
            float v3 = (acc[m][n][3] + bv) * post_scale;
            if (flags & 2) { v0 = tanhf(v0); v1 = tanhf(v1); v2 = tanhf(v2); v3 = tanhf(v3); }
            if ((flags & 8) && c >= 1024) {
                ushort4 o;
                o.x = f2bf(v0); o.y = f2bf(v1); o.z = f2bf(v2); o.w = f2bf(v3);
                *(ushort4*)&C2[(long long)(c - 1024) * 8192 + r0] = o;
            } else if (flags & 1) {
                Cb[(long long)(r0 + 0) * ldc + c] = f2bf(v0);
                Cb[(long long)(r0 + 1) * ldc + c] = f2bf(v1);
                Cb[(long long)(r0 + 2) * ldc + c] = f2bf(v2);
                Cb[(long long)(r0 + 3) * ldc + c] = f2bf(v3);
            } else {
                Cf[(long long)(r0 + 0) * ldc + c] = v0;
                Cf[(long long)(r0 + 1) * ldc + c] = v1;
                Cf[(long long)(r0 + 2) * ldc + c] = v2;
                Cf[(long long)(r0 + 3) * ldc + c] = v3;
            }
        }
    }
}

// ======= fused scores + softmax, BK=32 dbuf + counted vmcnt (R12-proven) ==========
__global__ __launch_bounds__(512, 1)
void scores_softmax(const ushort* __restrict__ qq, const ushort* __restrict__ kk,
                    float* __restrict__ attn, ushort* __restrict__ attnb)
{
    __shared__ ushort As[2][128 * 32];
    __shared__ ushort Bs[2][512 * 32];
    __shared__ float redm[4][128];
    __shared__ float reds[4][128];

    int z = blockIdx.z;              // n = h*16 + b
    int b = z & 15, h = z >> 4;
    const ushort* Abase = qq + (ll)b * 524288 + h * 256;
    const ushort* Bbase = kk + (ll)b * 524288 + h * 256;
    float*  aout = attn  + (ll)z * 262144;
    ushort* bout = attnb + (ll)z * 262144;

    int brow = blockIdx.y * 128;

    int t = threadIdx.x;
    int lane = t & 63, w = t >> 6;
    int wr = (w >> 2) * 64;
    int wc = (w & 3) * 128;

    int srow = t >> 2, sslot = t & 3;
    int sk = ((sslot ^ ((srow >> 1) & 3)) << 3);
    const ushort* ga = Abase + (ll)(brow + srow) * 1024 + sk;
    const ushort* gb = Bbase + (ll)srow * 1024 + sk;

    f32x4 acc[4][8] = {};

    auto stage = [&](int buf, int k0) {
        gload16(ga + k0, &As[buf][t * 8]);
        #pragma unroll
        for (int i = 0; i < 4; ++i)
            gload16(gb + (ll)(i * 128) * 1024 + k0, &Bs[buf][t * 8 + i * 4096]);
    };

    int cur = 0;
    stage(0, 0);
    #pragma unroll
    for (int tI = 0; tI < 8; ++tI) {
        if (tI + 1 < 8) {
            stage(cur ^ 1, (tI + 1) << 5);
            asm volatile("s_waitcnt vmcnt(5)" ::: "memory");
        } else {
            asm volatile("s_waitcnt vmcnt(0)" ::: "memory");
        }
        __builtin_amdgcn_s_barrier();
        __builtin_amdgcn_sched_barrier(0);

        int slot = (lane >> 4) ^ ((lane >> 1) & 3);
        const ushort* ab = &As[cur][(wr + (lane & 15)) * 32 + slot * 8];
        const ushort* bb = &Bs[cur][(wc + (lane & 15)) * 32 + slot * 8];
        bf16x8 af[4], bfr[8];
        #pragma unroll
        for (int m = 0; m < 4; ++m) af[m]  = *(const bf16x8*)(ab + m * 512);
        #pragma unroll
        for (int n = 0; n < 8; ++n) bfr[n] = *(const bf16x8*)(bb + n * 512);
        #pragma unroll
        for (int m = 0; m < 4; ++m)
            #pragma unroll
            for (int n = 0; n < 8; ++n)
                acc[m][n] = __builtin_amdgcn_mfma_f32_16x16x32_bf16(af[m], bfr[n], acc[m][n], 0, 0, 0);

        __builtin_amdgcn_s_barrier();
        __builtin_amdgcn_sched_barrier(0);
        cur ^= 1;
    }

    float rmax[4][4], rinv[4][4];
    #pragma unroll
    for (int m = 0; m < 4; ++m)
        #pragma unroll
        for (int j = 0; j < 4; ++j) {
            float pm = acc[m][0][j];
            #pragma unroll
            for (int n = 1; n < 8; ++n) pm = fmaxf(pm, acc[m][n][j]);
            pm = fmaxf(pm, __shfl_xor(pm, 1));
            pm = fmaxf(pm, __shfl_xor(pm, 2));
            pm = fmaxf(pm, __shfl_xor(pm, 4));
            pm = fmaxf(pm, __shfl_xor(pm, 8));
            if ((lane & 15) == 0)
                redm[w & 3][wr + m * 16 + (lane >> 4) * 4 + j] = pm;
        }
    __syncthreads();
    #pragma unroll
    for (int m = 0; m < 4; ++m)
        #pragma unroll
        for (int j = 0; j < 4; ++j) {
            int row = wr + m * 16 + (lane >> 4) * 4 + j;
            rmax[m][j] = fmaxf(fmaxf(redm[0][row], redm[1][row]),
                               fmaxf(redm[2][row], redm[3][row]));
        }
    #pragma unroll
    for (int m = 0; m < 4; ++m)
        #pragma unroll
        for (int j = 0; j < 4; ++j) {
            float ps = 0.f;
            #pragma unroll
            for (int n = 0; n < 8; ++n) {
                float e = __expf(acc[m][n][j] - rmax[m][j]);
                acc[m][n][j] = e;
                ps += e;
            }
            ps += __shfl_xor(ps, 1);
            ps += __shfl_xor(ps, 2);
            ps += __shfl_xor(ps, 4);
            ps += __shfl_xor(ps, 8);
            if ((lane & 15) == 0)
                reds[w & 3][wr + m * 16 + (lane >> 4) * 4 + j] = ps;
        }
    __syncthreads();
    #pragma unroll
    for (int m = 0; m < 4; ++m)
        #pragma unroll
        for (int j = 0; j < 4; ++j) {
            int row = wr + m * 16 + (lane >> 4) * 4 + j;
            rinv[m][j] = 1.0f / (reds[0][row] + reds[1][row] + reds[2][row] + reds[3][row]);
        }
    #pragma unroll
    for (int m = 0; m < 4; ++m) {
        int r0 = brow + wr + m * 16 + (lane >> 4) * 4;
        #pragma unroll
        for (int n = 0; n < 8; ++n) {
            int c = wc + n * 16 + (lane & 15);
            #pragma unroll
            for (int j = 0; j < 4; ++j) {
                float v = acc[m][n][j] * rinv[m][j];
                aout[(ll)(r0 + j) * 512 + c] = v;
                bout[(ll)(r0 + j) * 512 + c] = f2bf(v);
            }
        }
    }
}

// ================= merged prep kernels =================
__global__ __launch_bounds__(256)
void prep_acts(const float* __restrict__ query, const float* __restrict__ value,
               const float* __restrict__ prev, const float* __restrict__ cw,
               const float* __restrict__ cb,
               ushort* __restrict__ Acat, ushort* __restrict__ vext)
{
    int bI = blockIdx.x;
    if (bI < 16384) {
        const float* in = (bI < 8192) ? query : value;
        ushort* out = (bI < 8192) ? Acat : vext;
        int ld_out = (bI < 8192) ? 2048 : 1088;
        ll idx = (ll)(bI & 8191) * 256 + threadIdx.x;
        ll row = idx >> 8;
        int c4 = (int)(idx & 255) * 4;
        float4 v = *(const float4*)&in[row * 1024 + c4];
        ushort4 o;
        o.x = f2bf(v.x); o.y = f2bf(v.y); o.z = f2bf(v.z); o.w = f2bf(v.w);
        *(ushort4*)&out[row * ld_out + c4] = o;
    } else {
        int idx = (bI - 16384) * 256 + threadIdx.x;
        int row = idx >> 6, j = idx & 63;
        int b = row >> 9, l = row & 511;
        ushort v = 0;
        if (j < 40) {
            int h = j / 10, c = j - h * 10;
            const float* p = prev + (ll)(b * 4 + h) * VL_;
            float xm = (l > 0)       ? p[l - 1] : 0.f;
            float x0 = p[l];
            float xp = (l < VL_ - 1) ? p[l + 1] : 0.f;
            v = f2bf(xm * cw[c * 3 + 0] + x0 * cw[c * 3 + 1] + xp * cw[c * 3 + 2] + cb[c]);
        }
        vext[(ll)row * 1088 + 1024 + j] = v;
    }
}

// prep_w: blocks 0..1023 Wq->Wqb; 1024..2047 Wv->Wvb; 2048..2079 bias/wloc folds;
//         2080..2127 sw3 transpose (swq/swk/swv -> bf16 256x256 transposed)
__global__ __launch_bounds__(256)
void prep_w(const float* __restrict__ Wq, const float* __restrict__ Wv,
            ushort* __restrict__ Wqb, ushort* __restrict__ Wvb,
            const float* __restrict__ bq, const float* __restrict__ sbq, const float* __restrict__ swq,
            const float* __restrict__ bias, const float* __restrict__ sbk, const float* __restrict__ swk,
            const float* __restrict__ sbv, const float* __restrict__ swv,
            const float* __restrict__ Wloc,
            float* __restrict__ bqq, float* __restrict__ bkv,
            float* __restrict__ wlK, float* __restrict__ wlV,
            ushort* __restrict__ swqTb, ushort* __restrict__ swkTb, ushort* __restrict__ swvTb)
{
    __shared__ float tile[64][65];
    int bI = blockIdx.x;
    if (bI < 2048) {
        const float* in = (bI < 1024) ? Wq : Wv;
        ushort* out = (bI < 1024) ? Wqb : Wvb;
        ll idx = (ll)(bI & 1023) * 256 + threadIdx.x;
        ll row = idx >> 8;
        int c4 = (int)(idx & 255) * 4;
        float4 v = *(const float4*)&in[row * 1024 + c4];
        ushort4 o;
        o.x = f2bf(v.x); o.y = f2bf(v.y); o.z = f2bf(v.z); o.w = f2bf(v.w);
        *(ushort4*)&out[row * 1024 + c4] = o;
        return;
    }
    if (bI < 2080) {
        int idx = (bI - 2048) * 256 + threadIdx.x;
        if (idx < 1024) {
            int h = idx >> 8, d = idx & 255;
            float s = 0.f;
            for (int j = 0; j < 256; ++j) s += bq[h * 256 + j] * swq[j * 256 + d];
            bqq[idx] = s + sbq[d];
        } else if (idx < 3072) {
            int i = idx - 1024;
            int kv = i >> 10, ii = i & 1023;
            int h = ii >> 8, d = ii & 255;
            const float* sw = kv ? swv : swk;
            const float* sb = kv ? sbv : sbk;
            float s = 0.f;
            for (int j = 0; j < 256; ++j) s += bias[h * 256 + j] * sw[j * 256 + d];
            bkv[i] = s + sb[d];
        } else if (idx < 5632) {
            int i = idx - 3072; int c = i >> 8, d = i & 255;
            float s = 0.f;
            for (int j = 0; j < 256; ++j) s += Wloc[c * 256 + j] * swk[j * 256 + d];
            wlK[i] = s;
        } else if (idx < 8192) {
            int i = idx - 5632; int c = i >> 8, d = i & 255;
            float s = 0.f;
            for (int j = 0; j < 256; ++j) s += Wloc[c * 256 + j] * swv[j * 256 + d];
            wlV[i] = s;
        }
        return;
    }
    // sw3 transpose branch: 48 blocks (3 matrices x 4x4 tiles of 256x256)
    int i = bI - 2080;
    int zz = i >> 4, rem = i & 15;
    const float* in = (zz == 0) ? swq : (zz == 1) ? swk : swv;
    ushort* out     = (zz == 0) ? swqTb : (zz == 1) ? swkTb : swvTb;
    int r0 = (rem >> 2) * 64, c0 = (rem & 3) * 64;
    int t = threadIdx.x;
    int tr = t >> 2, tc = (t & 3) * 16;
    const float* ip = in + (ll)(r0 + tr) * 256 + c0 + tc;
    #pragma unroll
    for (int ii = 0; ii < 4; ++ii) {
        float4 v = *(const float4*)(ip + ii * 4);
        tile[tr][tc + ii * 4 + 0] = v.x;
        tile[tr][tc + ii * 4 + 1] = v.y;
        tile[tr][tc + ii * 4 + 2] = v.z;
        tile[tr][tc + ii * 4 + 3] = v.w;
    }
    __syncthreads();
    int cl = t >> 2, rl = (t & 3) * 16;
    ushort* op = out + (ll)(c0 + cl) * 256 + r0 + rl;
    #pragma unroll
    for (int ii = 0; ii < 16; ++ii) op[ii] = f2bf(tile[rl + ii][cl]);
}

__global__ __launch_bounds__(256)
void transpose_cast(const float* __restrict__ in, ushort* __restrict__ out, int R, int C, int ld_out)
{
    __shared__ float tile[64][65];
    int r0 = blockIdx.y * 64, c0 = blockIdx.x * 64;
    int t = threadIdx.x;
    int tr = t >> 2, tc = (t & 3) * 16;
    const float* ip = in + (ll)(r0 + tr) * C + c0 + tc;
    #pragma unroll
    for (int i = 0; i < 4; ++i) {
        float4 v = *(const float4*)(ip + i * 4);
        tile[tr][tc + i * 4 + 0] = v.x;
        tile[tr][tc + i * 4 + 1] = v.y;
        tile[tr][tc + i * 4 + 2] = v.z;
        tile[tr][tc + i * 4 + 3] = v.w;
    }
    __syncthreads();
    int cl = t >> 2, rl = (t & 3) * 16;
    ushort* op = out + (ll)(c0 + cl) * ld_out + r0 + rl;
    #pragma unroll
    for (int i = 0; i < 16; ++i) op[i] = f2bf(tile[rl + i][cl]);
}

__global__ __launch_bounds__(256)
void btext_fill(const float* __restrict__ wlK, const float* __restrict__ wlV,
                ushort* __restrict__ btExt)
{
    int idx = blockIdx.x * 256 + threadIdx.x;
    int n = idx >> 6, j = idx & 63;
    ushort v = 0;
    if (j < 40) {
        int hp = j / 10, c = j - hp * 10;
        int nn = n & 1023;
        int h = nn >> 8, d = nn & 255;
        if (hp == h) {
            const float* wl = (n >= 1024) ? wlV : wlK;
            v = f2bf(wl[c * 256 + d]);
        }
    }
    btExt[(ll)n * 1088 + 1024 + j] = v;
}

extern "C" void kernel_launch(void* const* d_in, const int* in_sizes, int n_in,
                              void* d_out, int out_size, void* d_ws, size_t ws_size,
                              hipStream_t stream)
{
    (void)in_sizes; (void)n_in; (void)out_size; (void)ws_size;

    const float* query = (const float*)d_in[0];
    const float* value = (const float*)d_in[1];
    const float* prev  = (const float*)d_in[2];
    const float* convw = (const float*)d_in[3];
    const float* convb = (const float*)d_in[4];
    const float* Wq    = (const float*)d_in[5];
    const float* bq    = (const float*)d_in[6];
    const float* Wv    = (const float*)d_in[7];
    const float* Wloc  = (const float*)d_in[8];
    const float* bias  = (const float*)d_in[9];
    const float* Wout  = (const float*)d_in[10];
    const float* bout  = (const float*)d_in[11];
    const float* swq   = (const float*)d_in[12];
    const float* sbq   = (const float*)d_in[13];
    const float* swk   = (const float*)d_in[14];
    const float* sbk   = (const float*)d_in[15];
    const float* swv   = (const float*)d_in[16];
    const float* sbv   = (const float*)d_in[17];

    float* out_buf  = (float*)d_out;                          // (B,QL,HID) f32
    float* attn_buf = out_buf + (ll)B_ * QL_ * HID_;          // (64,512,512) f32

    // ---- workspace layout, BYTE offsets (liveness-audited, total 146.44 MB) ----
    char* wsb = (char*)d_ws;
    ushort* vext   = (ushort*)(wsb + 0);           // 8192x1088 bf16 -> dead after kkvv
    ushort* WoutTb = (ushort*)(wsb + 0);           // 1024x2048 bf16 (after kkvv)
    ushort* kkb    = (ushort*)(wsb + 17825792);    // 8192x1024 bf16
    ushort* attnb  = (ushort*)(wsb + 34603008);    // 64*512*512 bf16
    ushort* Acat   = (ushort*)(wsb + 68157440);    // 8192x2048 bf16 (ctx | query)
    ushort* qqb    = (ushort*)(wsb + 101711872);   // 8192x1024 bf16
    ushort* vvT_b  = (ushort*)(wsb + 118489088);   // 1024x8192 bf16
    float*  bqq    = (float*)(wsb + 135266304);
    float*  bkv    = (float*)(wsb + 135270400);
    float*  wlK    = (float*)(wsb + 135278592);
    float*  wlV    = (float*)(wsb + 135288832);
    ushort* swqTb  = (ushort*)(wsb + 135299072);   // 256x256 bf16 (swk/swv contiguous)
    ushort* swkTb  = (ushort*)(wsb + 135430144);
    ushort* swvTb  = (ushort*)(wsb + 135561216);
    ushort* Wqb    = (ushort*)(wsb + 135692288);
    ushort* Wvb    = (ushort*)(wsb + 137789440);
    ushort* wqqTb  = (ushort*)(wsb + 139886592);
    ushort* btExt  = (ushort*)(wsb + 141983744);

    // --- merged precomputes (input-only deps) ---
    prep_acts<<<18432, 256, 0, stream>>>(query, value, prev, convw, convb, Acat + 1024, vext);
    prep_w<<<2128, 256, 0, stream>>>(Wq, Wv, Wqb, Wvb, bq, sbq, swq, bias, sbk, swk,
                                     sbv, swv, Wloc, bqq, bkv, wlK, wlV,
                                     swqTb, swkTb, swvTb);

    // folded weights via MFMA: wqqT, and [swk|swv] x Wv batched in ONE dispatch
    gemm_bf16<<<dim3(8, 2, 4), 256, 0, stream>>>(swqTb, Wqb, wqqTb, nullptr, nullptr,
        256, 256, 1024, 1024, 0, 0, 0, 256, 0, 262144, 1, 1.0f, 1);
    gemm_bf16<<<dim3(8, 2, 8), 256, 0, stream>>>(swkTb, Wvb, btExt, nullptr, nullptr,
        256, 256, 1024, 1088, 0, 65536, 256, 0, 278528, 1114112, 4, 1.0f, 1);
    btext_fill<<<512, 256, 0, stream>>>(wlK, wlV, btExt);

    // qq = (query @ Wqq + bqq) / 16 -> bf16
    gemm_bf16<<<dim3(8, 64, 1), 256, 0, stream>>>(Acat + 1024, wqqTb, qqb, nullptr, bqq,
        1024, 2048, 1024, 1024, 0, 0, 0, 0, 0, 0, 1, 0.0625f, 1);

    // kk|vv = [value|conv] @ [Wvk;wlK | Wvv;wlV] + bkv; kk->kkb, vv->vvT (transposed)
    gemm_bf16<<<dim3(16, 64, 1), 256, 0, stream>>>(vext, btExt, kkb, vvT_b, bkv,
        1088, 1088, 1088, 1024, 0, 0, 0, 0, 0, 0, 1, 1.0f, 1 | 8);

    // Wout^T bf16 into region A (vext dead after kkvv)
    transpose_cast<<<dim3(16, 32), 256, 0, stream>>>(Wout, WoutTb, 2048, 1024, 2048);

    // fused scores + softmax: attn f32 -> d_out, bf16 copy -> attnb
    scores_softmax<<<dim3(1, 4, 64), 512, 0, stream>>>(qqb, kkb, attn_buf, attnb);

    // ctx = attn @ vv -> bf16 into Acat left half (merged heads)
    gemm_bf16<<<dim3(2, 4, 64), 256, 0, stream>>>(attnb, vvT_b, Acat, nullptr, nullptr,
        512, 512, 8192, 2048,
        262144, 4194304, 512, 2097152, 1048576, 256, 16, 1.0f, 1);

    // out = tanh([ctx | query] @ Wout + bout) -> f32
    gemm_bf16<<<dim3(8, 64, 1), 256, 0, stream>>>(Acat, WoutTb, out_buf, nullptr, bout,
        2048, 2048, 2048, 1024, 0, 0, 0, 0, 0, 0, 1, 1.0f, 2);
}